// Round 2
// baseline (268.762 us; speedup 1.0000x reference)
//
#include <hip/hip_runtime.h>

// EWMA scan y_t = (1-a)*y_{t-1} + a*x_t as a single-pass decoupled-lookback
// chunked scan. L split into C=512 chunks of T=64 rows; each block owns one
// (chunk, column-group) tile of 64 rows x 256 cols, one column per thread,
// local scan held in registers. Inter-chunk carry via lookback over
// agent-scope (sc1) aggregate/prefix arrays in d_ws.

#define LT   32768
#define DC   1024
#define TCH  64
#define CCH  (LT / TCH)       // 512 chunks
#define NG   4                // column groups
#define CW   256              // columns per group
#define NBLK (CCH * NG)       // 2048 blocks

__device__ __forceinline__ void st_ws(float* p, float v) {
    __hip_atomic_store(p, v, __ATOMIC_RELAXED, __HIP_MEMORY_SCOPE_AGENT);
}
__device__ __forceinline__ float ld_ws(const float* p) {
    return __hip_atomic_load(p, __ATOMIC_RELAXED, __HIP_MEMORY_SCOPE_AGENT);
}

__global__ void ewma_clear(unsigned* __restrict__ w, int n) {
    int i = blockIdx.x * blockDim.x + threadIdx.x;
    if (i < n)
        __hip_atomic_store(&w[i], 0u, __ATOMIC_RELAXED, __HIP_MEMORY_SCOPE_AGENT);
}

__global__ void ewma_scan(const float* __restrict__ data,
                          const float* __restrict__ first,
                          const float* __restrict__ alpha_p,
                          float* __restrict__ out,
                          unsigned* __restrict__ ticket,
                          unsigned* __restrict__ flags,
                          float* __restrict__ agg,
                          float* __restrict__ pref) {
    __shared__ unsigned s_bid;
    __shared__ int s_n;
    __shared__ int s_pref;
    const int tid = threadIdx.x;
    if (tid == 0) s_bid = atomicAdd(ticket, 1u);
    __syncthreads();
    const unsigned vb = s_bid;
    const int c = (int)(vb >> 2);        // chunk index (ticket order => c waits only on smaller tickets)
    const int g = (int)(vb & 3u);        // column group
    const int col = g * CW + tid;
    const int chain = g * CCH;

    const float alpha = alpha_p[0];
    const float decay = 1.0f - alpha;
    float rT = decay;                    // decay^64 via 6 squarings
    rT *= rT; rT *= rT; rT *= rT; rT *= rT; rT *= rT; rT *= rT;

    // ---- local zero-init scan, held in registers ----
    const float* p = data + (size_t)c * TCH * DC + col;
    float z[TCH];
    float zz = 0.f;
#pragma unroll
    for (int i = 0; i < TCH; ++i) {
        zz = fmaf(decay, zz, alpha * p[(size_t)i * DC]);
        z[i] = zz;
    }

    // ---- publish aggregate (chunk-local end value) ----
    if (c > 0 && c < CCH - 1) {
        st_ws(&agg[(size_t)(chain + c) * CW + tid], zz);
        __syncthreads();   // all payload sc1-stores drained (vmcnt 0 before barrier)
        if (tid == 0)
            __hip_atomic_store(&flags[chain + c], 1u, __ATOMIC_RELEASE,
                               __HIP_MEMORY_SCOPE_AGENT);
    }

    // ---- resolve carry (y value entering this chunk) ----
    float carry;
    if (c == 0) {
        carry = first[col];
    } else {
        carry = 0.f;
        float rp = 1.f;
        int j = c - 1;                   // next predecessor chunk to consume
        for (;;) {
            // wave 0 probes up to 64 predecessor flags at once
            if (tid < 64) {
                int jj = j - tid;
                unsigned f = 0u;
                if (jj >= 0)
                    f = __hip_atomic_load(&flags[chain + jj], __ATOMIC_ACQUIRE,
                                          __HIP_MEMORY_SCOPE_AGENT);
                unsigned long long live = __ballot(f != 0u);
                unsigned long long prm  = __ballot(f == 2u);
                if (tid == 0) {
                    unsigned long long notlive = ~live;
                    int run    = (notlive == 0ull) ? 64 : (__ffsll((long long)notlive) - 1);
                    int pfirst = (prm == 0ull) ? 64 : (__ffsll((long long)prm) - 1);
                    if (pfirst < run) { s_n = pfirst + 1; s_pref = 1; }
                    else             { s_n = run;        s_pref = 0; }
                }
            }
            __syncthreads();
            const int n  = s_n;
            const int hp = s_pref;
            __syncthreads();
            if (n == 0) { __builtin_amdgcn_s_sleep(2); continue; }
            for (int k = 0; k < n; ++k) {
                const float* src = (hp && k == n - 1) ? pref : agg;
                float v = ld_ws(&src[(size_t)(chain + j - k) * CW + tid]);
                carry = fmaf(rp, v, carry);
                rp *= rT;
            }
            j -= n;
            if (hp) break;
        }
    }

    // ---- publish inclusive prefix (true y at chunk end) ----
    if (c < CCH - 1) {
        float y_end = fmaf(rT, carry, zz);
        st_ws(&pref[(size_t)(chain + c) * CW + tid], y_end);
        __syncthreads();
        if (tid == 0)
            __hip_atomic_store(&flags[chain + c], 2u, __ATOMIC_RELEASE,
                               __HIP_MEMORY_SCOPE_AGENT);
    }

    // ---- write outputs: y_i = z_i + decay^(i+1) * carry ----
    float* o = out + (size_t)c * TCH * DC + col;
    float w = decay;
    float y = 0.f;
#pragma unroll
    for (int i = 0; i < TCH; ++i) {
        y = fmaf(w, carry, z[i]);
        o[(size_t)i * DC] = y;
        w *= decay;
    }
    if (c == CCH - 1)
        out[(size_t)LT * DC + col] = y;   // last-row output
}

extern "C" void kernel_launch(void* const* d_in, const int* in_sizes, int n_in,
                              void* d_out, int out_size, void* d_ws, size_t ws_size,
                              hipStream_t stream) {
    const float* data    = (const float*)d_in[0];
    const float* first   = (const float*)d_in[1];
    const float* alpha_p = (const float*)d_in[2];
    float* out = (float*)d_out;

    float* agg  = (float*)d_ws;                         // NG*CCH*CW floats (2 MB)
    float* pref = agg + (size_t)NG * CCH * CW;          // 2 MB
    unsigned* flags  = (unsigned*)(pref + (size_t)NG * CCH * CW);  // NG*CCH
    unsigned* ticket = flags + NG * CCH;                 // 1

    const int nclear = NG * CCH + 1;
    ewma_clear<<<(nclear + 255) / 256, 256, 0, stream>>>(flags, nclear);

    ewma_scan<<<NBLK, 256, 0, stream>>>(
        data, first, alpha_p, out, ticket, flags, agg, pref);
}

// Round 4
// 84.499 us; speedup vs baseline: 3.1807x; 3.1807x over previous
//
#include <hip/hip_runtime.h>

// EWMA scan y_t = (1-a)*y_{t-1} + a*x_t, y_{-1} = first_offset.
// 3-phase chunked scan, no spills, no cross-block spin:
//   phase1: per-chunk zero-init local scan end values (aggregates)
//   phase2: inter-chunk scan, one wave per column (Kogge-Stone over lanes)
//   phase3: recompute local scan (data re-read served by L3), add decayed
//           carry, nontemporal-store output so `data` stays L3-resident.

#define LT   32768
#define DC   1024
#define TCH  32               // timesteps per chunk
#define CCH  (LT / TCH)       // 1024 chunks
#define TPB  256
#define D4   (DC / 4)         // 256 float4 per row

typedef float nf4 __attribute__((ext_vector_type(4)));  // native vec for builtins

__global__ void ewma_phase1(const nf4* __restrict__ data4,
                            nf4* __restrict__ zend4,
                            const float* __restrict__ alpha_p) {
    const float alpha = alpha_p[0];
    const float decay = 1.0f - alpha;
    const int tid = threadIdx.x;    // float4 column group
    const int c = blockIdx.x;       // chunk index
    const nf4* p = data4 + (size_t)c * TCH * D4 + tid;
    float z0 = 0.f, z1 = 0.f, z2 = 0.f, z3 = 0.f;
#pragma unroll 8
    for (int i = 0; i < TCH; ++i) {
        nf4 x = p[(size_t)i * D4];
        z0 = fmaf(decay, z0, alpha * x.x);
        z1 = fmaf(decay, z1, alpha * x.y);
        z2 = fmaf(decay, z2, alpha * x.z);
        z3 = fmaf(decay, z3, alpha * x.w);
    }
    nf4 zv; zv.x = z0; zv.y = z1; zv.z = z2; zv.w = z3;
    zend4[c * D4 + tid] = zv;
}

// One wave per column d. Lane l owns chunks [l*CPL, (l+1)*CPL).
// Inter-chunk recurrence: S_c = r * S_{c-1} + e_c, r = decay^TCH.
__global__ void ewma_phase2(const float* __restrict__ zend,
                            const float* __restrict__ first,
                            float* __restrict__ carry,
                            const float* __restrict__ alpha_p) {
    const float alpha = alpha_p[0];
    const float decay = 1.0f - alpha;
    float r = decay;                 // decay^TCH via 5 squarings (TCH=32)
    r *= r; r *= r; r *= r; r *= r; r *= r;

    const int lane = threadIdx.x & 63;
    const int d = (blockIdx.x * blockDim.x + threadIdx.x) >> 6;  // column
    constexpr int CPL = CCH / 64;   // 16 chunks per lane

    float e[CPL];
#pragma unroll
    for (int j = 0; j < CPL; ++j)
        e[j] = zend[(lane * CPL + j) * DC + d];

    // lane-local aggregate with ratio r, zero init
    float A = 0.f;
#pragma unroll
    for (int j = 0; j < CPL; ++j) A = fmaf(r, A, e[j]);

    // q = r^CPL (ratio between consecutive lane aggregates), CPL=16
    float q = r;
    q *= q; q *= q; q *= q; q *= q;

    // Kogge-Stone inclusive scan across 64 lanes
    float y = A;
    float p = q;
#pragma unroll
    for (int o = 1; o < 64; o <<= 1) {
        float prev = __shfl_up(y, o, 64);
        if (lane >= o) y = fmaf(p, prev, y);
        p = p * p;
    }
    float excl = __shfl_up(y, 1, 64);
    if (lane == 0) excl = 0.f;

    // decayed first_offset contribution: q^lane
    float qpow = 1.f;
    {
        float base = q;
        int e2 = lane;
        while (e2) { if (e2 & 1) qpow *= base; base *= base; e2 >>= 1; }
    }
    float S = fmaf(qpow, first[d], excl);  // carry entering lane's first chunk

#pragma unroll
    for (int j = 0; j < CPL; ++j) {
        const int c = lane * CPL + j;
        carry[c * DC + d] = S;             // carry-in for chunk c
        S = fmaf(r, S, e[j]);
    }
}

__global__ void ewma_phase3(const nf4* __restrict__ data4,
                            const nf4* __restrict__ carry4,
                            nf4* __restrict__ out4,
                            nf4* __restrict__ out_last4,
                            const float* __restrict__ alpha_p) {
    const float alpha = alpha_p[0];
    const float decay = 1.0f - alpha;
    const int tid = threadIdx.x;
    const int c = blockIdx.x;
    const nf4 cin = carry4[c * D4 + tid];
    const nf4* p = data4 + (size_t)c * TCH * D4 + tid;
    nf4* o = out4 + (size_t)c * TCH * D4 + tid;
    float z0 = 0.f, z1 = 0.f, z2 = 0.f, z3 = 0.f, pw = 1.f;
#pragma unroll 8
    for (int i = 0; i < TCH; ++i) {
        nf4 x = p[(size_t)i * D4];
        z0 = fmaf(decay, z0, alpha * x.x);
        z1 = fmaf(decay, z1, alpha * x.y);
        z2 = fmaf(decay, z2, alpha * x.z);
        z3 = fmaf(decay, z3, alpha * x.w);
        pw *= decay;
        nf4 yv;
        yv.x = fmaf(pw, cin.x, z0);
        yv.y = fmaf(pw, cin.y, z1);
        yv.z = fmaf(pw, cin.z, z2);
        yv.w = fmaf(pw, cin.w, z3);
        // nontemporal: don't let `out` evict `data` from L3 (phase3's reads
        // are served by L3 only if phase1's footprint stays resident).
        __builtin_nontemporal_store(yv, &o[(size_t)i * D4]);
    }
    if (c == CCH - 1) {
        nf4 yl;
        yl.x = fmaf(pw, cin.x, z0);
        yl.y = fmaf(pw, cin.y, z1);
        yl.z = fmaf(pw, cin.z, z2);
        yl.w = fmaf(pw, cin.w, z3);
        out_last4[tid] = yl;
    }
}

extern "C" void kernel_launch(void* const* d_in, const int* in_sizes, int n_in,
                              void* d_out, int out_size, void* d_ws, size_t ws_size,
                              hipStream_t stream) {
    const float* data    = (const float*)d_in[0];
    const float* first   = (const float*)d_in[1];
    const float* alpha_p = (const float*)d_in[2];
    float* out = (float*)d_out;

    float* zend  = (float*)d_ws;              // CCH*DC floats = 4 MB
    float* carry = zend + (size_t)CCH * DC;   // CCH*DC floats = 4 MB

    ewma_phase1<<<CCH, TPB, 0, stream>>>(
        (const nf4*)data, (nf4*)zend, alpha_p);

    ewma_phase2<<<DC / (TPB / 64), TPB, 0, stream>>>(
        zend, first, carry, alpha_p);

    ewma_phase3<<<CCH, TPB, 0, stream>>>(
        (const nf4*)data, (const nf4*)carry, (nf4*)out,
        (nf4*)(out + (size_t)LT * DC), alpha_p);
}